// Round 5
// baseline (198.706 us; speedup 1.0000x reference)
//
#include <hip/hip_runtime.h>

// Causal MHA forward, B=2 T=2048 C=1024 H=16 hs=64, fp32 in/out, bf16 MFMA internally.
// R5: flash BQ=128 (4 waves x 32q, K/V frag reads amortized over 2 q-strips), rotation-
// swizzled LDS (stride 64, chunk (cb+row)&7 -> conflict-free), kv-split m>=10;
// qkv back to 4-wave 64x64/wave; proj 128x128/8-wave.

typedef unsigned short u16;
typedef unsigned int u32;
typedef __bf16 bf16x8 __attribute__((ext_vector_type(8)));
typedef float f32x4 __attribute__((ext_vector_type(4)));
typedef u32 u32x4 __attribute__((ext_vector_type(4)));
typedef u16 u16x4 __attribute__((ext_vector_type(4)));

__constant__ signed char JM[22] = {9,8,7,15,15,14,14,6,13,13,12,12,5,11,11,10,10,4,3,2,1,0};
__constant__ signed char JH[22] = {0,0,0,1, 2, 1, 2, 0,1, 2, 1, 2, 0,1, 2, 1, 2, 0,0,0,0,0};

__device__ __forceinline__ u16 f2bf(float f) {
  u32 u = __float_as_uint(f);
  u32 r = u + 0x7FFFu + ((u >> 16) & 1u);  // RNE, finite inputs only
  return (u16)(r >> 16);
}

__device__ __forceinline__ bf16x8 ld_bf8(const u16* p) {
  union { u32x4 u; bf16x8 b; } x;
  x.u = *(const u32x4*)p;
  return x.b;
}

__device__ __forceinline__ void gld_lds16(const u16* g, u16* l) {
  __builtin_amdgcn_global_load_lds(
      (const __attribute__((address_space(1))) u32*)g,
      (__attribute__((address_space(3))) u32*)l, 16, 0, 0);
}

// ---- fp32 -> bf16, 8 elements/thread ----
__global__ __launch_bounds__(256) void conv_x_kernel(const float* __restrict__ src,
                                                     u16* __restrict__ dst) {
  int idx = blockIdx.x * 256 + threadIdx.x;
  const float4* s4 = (const float4*)src;
  float4 a = s4[2 * idx], b = s4[2 * idx + 1];
  union { u16 h[8]; u32x4 v; } pk;
  pk.h[0] = f2bf(a.x); pk.h[1] = f2bf(a.y); pk.h[2] = f2bf(a.z); pk.h[3] = f2bf(a.w);
  pk.h[4] = f2bf(b.x); pk.h[5] = f2bf(b.y); pk.h[6] = f2bf(b.z); pk.h[7] = f2bf(b.w);
  *(u32x4*)&dst[(size_t)idx * 8] = pk.v;
}

// ---- fp32 (R x Cc) -> bf16 transposed (Cc x R) ----
__global__ __launch_bounds__(256) void convT_kernel(const float* __restrict__ src,
                                                    u16* __restrict__ dst, int R, int Cc) {
  __shared__ float ls[64][65];
  int r0 = blockIdx.x * 64, c0 = blockIdx.y * 64;
  int t = threadIdx.x;
  for (int u = t; u < 1024; u += 256) {
    int r = u >> 4, cs = (u & 15) << 2;
    float4 v = *(const float4*)&src[(size_t)(r0 + r) * Cc + (c0 + cs)];
    ls[r][cs] = v.x; ls[r][cs + 1] = v.y; ls[r][cs + 2] = v.z; ls[r][cs + 3] = v.w;
  }
  __syncthreads();
  for (int u = t; u < 1024; u += 256) {
    int n = u >> 4, ks = (u & 15) << 2;
    u16x4 o;
    o.x = f2bf(ls[ks][n]); o.y = f2bf(ls[ks + 1][n]);
    o.z = f2bf(ls[ks + 2][n]); o.w = f2bf(ls[ks + 3][n]);
    *(u16x4*)&dst[(size_t)(c0 + n) * R + (r0 + ks)] = o;
  }
}

// ---- QKV GEMM: 128x128 tile, 4 waves x (64x64), BK=32, K=1024 (m97 structure) ----
__global__ __launch_bounds__(256) void qkv_gemm_kernel(
    const u16* __restrict__ A, const u16* __restrict__ Bt,
    u16* __restrict__ Qh, u16* __restrict__ Kh, u16* __restrict__ Vh, float qscale) {
  constexpr int K = 1024;
  __shared__ __align__(16) u16 As[128 * 32];
  __shared__ __align__(16) u16 Bs[128 * 32];
  int t = threadIdx.x;
  int wave = t >> 6, lane = t & 63, quad = lane >> 4, l16 = lane & 15;
  int wm = (wave >> 1) << 6, wn = (wave & 1) << 6;
  int m0 = blockIdx.x * 128, n0 = blockIdx.y * 128;
  f32x4 acc[4][4] = {};
  int u0 = t, u1 = t + 256;  // 512 units of 16B per matrix
  int ra0 = u0 >> 2, ca0 = ((u0 & 3) ^ ((u0 >> 3) & 3)) << 3;
  int ra1 = u1 >> 2, ca1 = ((u1 & 3) ^ ((u1 >> 3) & 3)) << 3;
  int swq = (quad ^ ((l16 >> 1) & 3)) << 3;
  for (int k0 = 0; k0 < K; k0 += 32) {
    gld_lds16(&A[(size_t)(m0 + ra0) * K + k0 + ca0], &As[u0 * 8]);
    gld_lds16(&A[(size_t)(m0 + ra1) * K + k0 + ca1], &As[u1 * 8]);
    gld_lds16(&Bt[(size_t)(n0 + ra0) * K + k0 + ca0], &Bs[u0 * 8]);
    gld_lds16(&Bt[(size_t)(n0 + ra1) * K + k0 + ca1], &Bs[u1 * 8]);
    __syncthreads();
    bf16x8 af[4], bfr[4];
    for (int r = 0; r < 4; ++r) af[r] = ld_bf8(&As[(wm + r * 16 + l16) * 32 + swq]);
    for (int c = 0; c < 4; ++c) bfr[c] = ld_bf8(&Bs[(wn + c * 16 + l16) * 32 + swq]);
    for (int r = 0; r < 4; ++r)
      for (int c = 0; c < 4; ++c)
        acc[r][c] = __builtin_amdgcn_mfma_f32_16x16x32_bf16(af[r], bfr[c], acc[r][c], 0, 0, 0);
    __syncthreads();
  }
  for (int r = 0; r < 4; ++r) {
    int rowbase = m0 + wm + r * 16 + quad * 4;
    for (int c = 0; c < 4; ++c) {
      int col = n0 + wn + c * 16 + l16;
      int seg = col >> 10;
      int cc = col & 1023;
      int h = cc >> 6, d = cc & 63;
      for (int i = 0; i < 4; ++i) {
        int row = rowbase + i;
        int b = row >> 11, tt = row & 2047;
        size_t off = (((size_t)(b * 16 + h)) * 2048 + tt) * 64 + d;
        float v = acc[r][c][i];
        if (seg == 0)      Qh[off] = f2bf(v * qscale);
        else if (seg == 1) Kh[off] = f2bf(v);
        else               Vh[off] = f2bf(v);
      }
    }
  }
}

// ---- bf16 transpose: Vh[bh][2048][64] -> Vt[bh][64][2048] ----
__global__ __launch_bounds__(256) void vT_kernel(const u16* __restrict__ Vh,
                                                 u16* __restrict__ Vt) {
  __shared__ __align__(16) u16 ls[64 * 72];
  int t = threadIdx.x;
  int t0 = blockIdx.x * 64, bh = blockIdx.y;
  const u16* in = Vh + ((size_t)bh * 2048 + t0) * 64;
  for (int u = t; u < 512; u += 256) {
    int row = u >> 3, col = (u & 7) << 3;
    *(u32x4*)&ls[row * 72 + col] = *(const u32x4*)&in[(size_t)row * 64 + col];
  }
  __syncthreads();
  for (int u = t; u < 512; u += 256) {
    int d = u >> 3, tc = (u & 7) << 3;
    union { u16 h[8]; u32x4 v; } pk;
    for (int j = 0; j < 8; ++j) pk.h[j] = ls[(tc + j) * 72 + d];
    *(u32x4*)&Vt[((size_t)bh * 64 + d) * 2048 + t0 + tc] = pk.v;
  }
}

// ---- proj GEMM: 128x128 tile, 8 waves (2x4 grid, wave tile 64x32), grid (32,8) ----
__global__ __launch_bounds__(512) void proj_gemm_kernel(
    const u16* __restrict__ A, const u16* __restrict__ Bt,
    float* __restrict__ out, const float* __restrict__ bias) {
  constexpr int K = 1024;
  __shared__ __align__(16) u16 As[128 * 32];
  __shared__ __align__(16) u16 Bs[128 * 32];
  int t = threadIdx.x;
  int wave = t >> 6, lane = t & 63, quad = lane >> 4, l16 = lane & 15;
  int wm = (wave >> 2) << 6, wn = (wave & 3) << 5;
  int m0 = blockIdx.x * 128, n0 = blockIdx.y * 128;
  f32x4 acc[4][2] = {};
  int u0 = t;  // 512 units of 16B per matrix, 1/thread
  int ra0 = u0 >> 2, ca0 = ((u0 & 3) ^ ((u0 >> 3) & 3)) << 3;
  int swq = (quad ^ ((l16 >> 1) & 3)) << 3;
  for (int k0 = 0; k0 < K; k0 += 32) {
    gld_lds16(&A[(size_t)(m0 + ra0) * K + k0 + ca0], &As[u0 * 8]);
    gld_lds16(&Bt[(size_t)(n0 + ra0) * K + k0 + ca0], &Bs[u0 * 8]);
    __syncthreads();
    bf16x8 af[4], bfr[2];
    for (int r = 0; r < 4; ++r) af[r] = ld_bf8(&As[(wm + r * 16 + l16) * 32 + swq]);
    for (int c = 0; c < 2; ++c) bfr[c] = ld_bf8(&Bs[(wn + c * 16 + l16) * 32 + swq]);
    for (int r = 0; r < 4; ++r)
      for (int c = 0; c < 2; ++c)
        acc[r][c] = __builtin_amdgcn_mfma_f32_16x16x32_bf16(af[r], bfr[c], acc[r][c], 0, 0, 0);
    __syncthreads();
  }
  for (int r = 0; r < 4; ++r) {
    int rowbase = m0 + wm + r * 16 + quad * 4;
    for (int c = 0; c < 2; ++c) {
      int col = n0 + wn + c * 16 + l16;
      float bv = bias[col];
      for (int i = 0; i < 4; ++i)
        out[(size_t)(rowbase + i) * 1024 + col] = acc[r][c][i] + bv;
    }
  }
}

// ---- flash attention: BQ=128, BN=64, 4 waves x 32 q-rows, static-max exp2 softmax ----
// S^T form (A=K, B=Q). Rotation-swizzled LDS (stride 64 u16, 16B chunk cb at (cb+row)&7).
// Jobs per bh: full m=0..9; m=10..15 kv-split into 2 halves -> fp32 partials + combine.
__global__ __launch_bounds__(256) void flash_kernel(
    const u16* __restrict__ Qh, const u16* __restrict__ Kh, const u16* __restrict__ Vt,
    u16* __restrict__ yb, float* __restrict__ Opart) {
  __shared__ __align__(16) u16 Ks[64 * 64];
  __shared__ __align__(16) u16 Vs[64 * 64];
  __shared__ __align__(16) u16 Ps[128 * 64];
  int t = threadIdx.x, wave = t >> 6, lane = t & 63, quad = lane >> 4, l16 = lane & 15;
  int jx = blockIdx.x, bh = blockIdx.y;
  int m = JM[jx], jh = JH[jx];
  int kvs = (jh == 2) ? (m + 1) : 0;
  int kve = (jh == 1) ? (m + 1) : (2 * m + 2);
  bool partial = jh != 0;
  int q0 = m << 7;
  const u16* Qb = Qh + (size_t)bh * 2048 * 64;
  const u16* Kb = Kh + (size_t)bh * 2048 * 64;
  const u16* Vb = Vt + (size_t)bh * 64 * 2048;
  bf16x8 qa[2][2];  // B-operand frags for 2 q-strips x 2 k-halves
  for (int s = 0; s < 2; ++s) {
    int qrow = q0 + wave * 32 + s * 16 + l16;
    qa[s][0] = ld_bf8(&Qb[(size_t)qrow * 64 + quad * 8]);
    qa[s][1] = ld_bf8(&Qb[(size_t)qrow * 64 + 32 + quad * 8]);
  }
  f32x4 oacc[2][4] = {};
  float ls0 = 0.f, ls1 = 0.f;
  // staging: 512 units of 16B per array; unit u: row u>>3, chunk u&7; swizzled LDS slot
  int ua = t, ub = t + 256;
  int ra = ua >> 3, cba = ua & 7, rb = ub >> 3, cbb = ub & 7;
  int lka = ra * 64 + ((cba + ra) & 7) * 8;
  int lkb = rb * 64 + ((cbb + rb) & 7) * 8;
  u32x4 kreg0, kreg1, vreg0, vreg1;
  {
    int kv0 = kvs << 6;
    kreg0 = *(const u32x4*)&Kb[(size_t)(kv0 + ra) * 64 + cba * 8];
    kreg1 = *(const u32x4*)&Kb[(size_t)(kv0 + rb) * 64 + cbb * 8];
    vreg0 = *(const u32x4*)&Vb[(size_t)ra * 2048 + kv0 + cba * 8];
    vreg1 = *(const u32x4*)&Vb[(size_t)rb * 2048 + kv0 + cbb * 8];
  }
  for (int j = kvs; j < kve; ++j) {
    int kv0 = j << 6;
    __syncthreads();
    *(u32x4*)&Ks[lka] = kreg0;
    *(u32x4*)&Ks[lkb] = kreg1;
    *(u32x4*)&Vs[lka] = vreg0;
    *(u32x4*)&Vs[lkb] = vreg1;
    __syncthreads();
    if (j + 1 < kve) {
      int kn = (j + 1) << 6;
      kreg0 = *(const u32x4*)&Kb[(size_t)(kn + ra) * 64 + cba * 8];
      kreg1 = *(const u32x4*)&Kb[(size_t)(kn + rb) * 64 + cbb * 8];
      vreg0 = *(const u32x4*)&Vb[(size_t)ra * 2048 + kn + cba * 8];
      vreg1 = *(const u32x4*)&Vb[(size_t)rb * 2048 + kn + cbb * 8];
    }
    bool maskit = (j >= 2 * m);  // diagonal-crossing kv tiles
    for (int c = 0; c < 4; ++c) {
      int krow = c * 16 + l16;
      bf16x8 kb0 = ld_bf8(&Ks[krow * 64 + ((quad + krow) & 7) * 8]);
      bf16x8 kb1 = ld_bf8(&Ks[krow * 64 + ((quad + 4 + krow) & 7) * 8]);
      for (int s = 0; s < 2; ++s) {
        f32x4 z = {0.f, 0.f, 0.f, 0.f};
        z = __builtin_amdgcn_mfma_f32_16x16x32_bf16(kb0, qa[s][0], z, 0, 0, 0);
        z = __builtin_amdgcn_mfma_f32_16x16x32_bf16(kb1, qa[s][1], z, 0, 0, 0);
        int prow = wave * 32 + s * 16 + l16;  // q-local row
        union { u16 hh[4]; u16x4 v; } pk;
        float lsadd = 0.f;
        for (int i = 0; i < 4; ++i) {
          float p = __builtin_amdgcn_exp2f(z[i]);
          if (maskit && (kv0 + c * 16 + quad * 4 + i > q0 + prow)) p = 0.f;
          lsadd += p;
          pk.hh[i] = f2bf(p);
        }
        if (s) ls1 += lsadd; else ls0 += lsadd;
        // logical col = c*16+quad*4; chunk = 2c+(quad>>1), sub-off (quad&1)*4
        *(u16x4*)&Ps[prow * 64 + ((2 * c + (quad >> 1) + prow) & 7) * 8 + (quad & 1) * 4] = pk.v;
      }
    }
    bf16x8 pa[2][2];  // per-wave private rows: no barrier needed
    for (int s = 0; s < 2; ++s) {
      int prow = wave * 32 + s * 16 + l16;
      pa[s][0] = ld_bf8(&Ps[prow * 64 + ((quad + prow) & 7) * 8]);
      pa[s][1] = ld_bf8(&Ps[prow * 64 + ((quad + 4 + prow) & 7) * 8]);
    }
    for (int dt = 0; dt < 4; ++dt) {
      int vrow = dt * 16 + l16;
      bf16x8 vb0 = ld_bf8(&Vs[vrow * 64 + ((quad + vrow) & 7) * 8]);
      bf16x8 vb1 = ld_bf8(&Vs[vrow * 64 + ((quad + 4 + vrow) & 7) * 8]);
      for (int s = 0; s < 2; ++s) {
        oacc[s][dt] = __builtin_amdgcn_mfma_f32_16x16x32_bf16(pa[s][0], vb0, oacc[s][dt], 0, 0, 0);
        oacc[s][dt] = __builtin_amdgcn_mfma_f32_16x16x32_bf16(pa[s][1], vb1, oacc[s][dt], 0, 0, 0);
      }
    }
  }
  ls0 += __shfl_xor(ls0, 16); ls0 += __shfl_xor(ls0, 32);
  ls1 += __shfl_xor(ls1, 16); ls1 += __shfl_xor(ls1, 32);
  if (partial) {
    float* Op = Opart + ((size_t)(bh * 6 + (m - 10)) * 2 + (jh - 1)) * 8320;
    for (int s = 0; s < 2; ++s)
      for (int dt = 0; dt < 4; ++dt)
        for (int i = 0; i < 4; ++i)
          Op[(wave * 32 + s * 16 + quad * 4 + i) * 64 + dt * 16 + l16] = oacc[s][dt][i];
    if (quad == 0) {
      Op[8192 + wave * 32 + l16] = ls0;
      Op[8192 + wave * 32 + 16 + l16] = ls1;
    }
  } else {
    int b = bh >> 4, hh = bh & 15;
    for (int s = 0; s < 2; ++s) {
      float lss = s ? ls1 : ls0;
      for (int i = 0; i < 4; ++i) {
        float inv = 1.0f / __shfl(lss, quad * 4 + i);
        int qq = q0 + wave * 32 + s * 16 + quad * 4 + i;
        size_t rowoff = ((size_t)(b * 2048 + qq)) * 1024 + hh * 64;
        for (int dt = 0; dt < 4; ++dt)
          yb[rowoff + dt * 16 + l16] = f2bf(oacc[s][dt][i] * inv);
      }
    }
  }
}

// ---- combine split halves: O = O0+O1, l = l0+l1, write normalized bf16 ----
__global__ __launch_bounds__(256) void combine_kernel(const float* __restrict__ Opart,
                                                      u16* __restrict__ yb) {
  int sx = blockIdx.x, bh = blockIdx.y, t = threadIdx.x;
  int m = 10 + sx;
  const float* A = Opart + (size_t)(bh * 6 + sx) * 2 * 8320;
  const float* Bp = A + 8320;
  int q = t >> 1, d0 = (t & 1) << 5;  // 128 rows x 64 cols, 2 threads/row
  float inv = 1.0f / (A[8192 + q] + Bp[8192 + q]);
  int b = bh >> 4, h = bh & 15;
  size_t off = ((size_t)(b * 2048 + (m << 7) + q)) * 1024 + h * 64 + d0;
  for (int k0 = 0; k0 < 32; k0 += 8) {
    union { u16 hh[8]; u32x4 v; } pk;
    for (int k = 0; k < 8; ++k)
      pk.hh[k] = f2bf((A[q * 64 + d0 + k0 + k] + Bp[q * 64 + d0 + k0 + k]) * inv);
    *(u32x4*)&yb[off + k0] = pk.v;
  }
}

extern "C" void kernel_launch(void* const* d_in, const int* in_sizes, int n_in,
                              void* d_out, int out_size, void* d_ws, size_t ws_size,
                              hipStream_t stream) {
  const float* x     = (const float*)d_in[0];
  const float* Wkqv  = (const float*)d_in[1];
  const float* Wproj = (const float*)d_in[2];
  const float* bproj = (const float*)d_in[3];
  float* out = (float*)d_out;

  u16* ws     = (u16*)d_ws;                       // 48 MB total scratch
  u16* xb     = ws;                               // 4096x1024 bf16 (dead after qkv)
  u16* wkqvT  = xb + (size_t)4096 * 1024;         // 3072x1024 (dead after qkv)
  u16* wprojT = wkqvT + (size_t)3072 * 1024;      // 1024x1024 (W_proj^T)
  u16* Qh     = wprojT + (size_t)1024 * 1024;     // [32][2048][64], pre-scaled
  u16* Kh     = Qh + (size_t)32 * 2048 * 64;      // [32][2048][64]
  u16* Vt     = Kh + (size_t)32 * 2048 * 64;      // [32][64][2048]
  u16* yb     = Vt + (size_t)32 * 2048 * 64;      // 4096x1024 attn out; doubles as Vh
  u16* Vh     = yb;
  float* Opart = (float*)ws;  // aliases xb+wkqvT (12.8 MB < 14 MB), live after qkv only

  const float QSCALE = 0.18033688011112042f;  // (1/sqrt(64)) * log2(e)

  conv_x_kernel<<<2048, 256, 0, stream>>>(x, xb);
  convT_kernel<<<dim3(16, 48), 256, 0, stream>>>(Wkqv, wkqvT, 1024, 3072);
  convT_kernel<<<dim3(16, 16), 256, 0, stream>>>(Wproj, wprojT, 1024, 1024);
  qkv_gemm_kernel<<<dim3(32, 24), 256, 0, stream>>>(xb, wkqvT, Qh, Kh, Vh, QSCALE);
  vT_kernel<<<dim3(32, 32), 256, 0, stream>>>(Vh, Vt);
  flash_kernel<<<dim3(22, 32), 256, 0, stream>>>(Qh, Kh, Vt, yb, Opart);
  combine_kernel<<<dim3(6, 32), 256, 0, stream>>>(Opart, yb);
  proj_gemm_kernel<<<dim3(32, 8), 512, 0, stream>>>(yb, wprojT, out, bproj);
}